// Round 7
// baseline (6005.445 us; speedup 1.0000x reference)
//
#include <hip/hip_runtime.h>
#include <math.h>

#define B_   4
#define T_   20000
#define SUB  20
#define ENO  2000
#define INO  500
#define HID  10
#define NCOS 24
#define TNO  200
#define NSL  25      // 20 E slices + 5 I slices, each 100 e wide
#define SLW  100     // slice width (floats)
#define ROWS 64      // t-rows per block

// ---------------- prep 1: softmax over subunit axis; CwP[z][s][100] = C*exp(scale) (slice-contiguous); e2 = exp(W2)
__global__ __launch_bounds__(256) void prep1_kernel(
    const float* __restrict__ Ce_raw, const float* __restrict__ Ci_raw,
    const float* __restrict__ ge, const float* __restrict__ gi,
    const float* __restrict__ Es, const float* __restrict__ Is,
    const float* __restrict__ W2, const int* __restrict__ testp,
    float* __restrict__ outCe, float* __restrict__ outCi,
    float* __restrict__ CwP, float* __restrict__ e2)
{
  int idx = blockIdx.x * 256 + threadIdx.x;
  int test = *testp;
  float scale = test ? 10000.f : 1000.f;
  if (idx < ENO + INO) {
    const float* raw; const float* g; float* outC; int n, col, zbase; float sc;
    if (idx < ENO) { raw = Ce_raw; g = ge; outC = outCe; n = ENO; col = idx;       zbase = 0;  sc = expf(Es[col]); }
    else           { raw = Ci_raw; g = gi; outC = outCi; n = INO; col = idx - ENO; zbase = 20; sc = expf(Is[col]); }
    float v[SUB]; float m = -1e30f;
    #pragma unroll
    for (int s = 0; s < SUB; s++) {
      float x = raw[s * n + col];
      if (!test) x += g[s * n + col];
      x *= scale;
      v[s] = x; m = fmaxf(m, x);
    }
    float sum = 0.f;
    #pragma unroll
    for (int s = 0; s < SUB; s++) { v[s] = expf(v[s] - m); sum += v[s]; }
    float inv = 1.f / sum;
    int z = zbase + col / SLW, ep = col % SLW;
    #pragma unroll
    for (int s = 0; s < SUB; s++) {
      float c = v[s] * inv;
      outC[s * n + col] = c;
      CwP[((long)z * SUB + s) * SLW + ep] = c * sc;
    }
  } else if (idx < ENO + INO + SUB * HID) {
    int j = idx - (ENO + INO);
    e2[j] = expf(W2[j]);
  }
}

// ---------------- prep 2: effective kernels Keff[src][s][h][d] = sum_k W[s*HID+h,k] * basis(k,d)
__global__ __launch_bounds__(256) void prep2_kernel(
    const float* __restrict__ We, const float* __restrict__ Wi, float* __restrict__ Keff)
{
  int idx = blockIdx.x * 256 + threadIdx.x;
  if (idx >= 2 * SUB * HID * TNO) return;
  int d   = idx % TNO;
  int sh  = (idx / TNO) % (SUB * HID);
  int src = idx / (TNO * SUB * HID);
  const float* W = src ? Wi : We;           // [SUB*HID][NCOS]
  const float PIF = 3.14159265358979323846f;
  float raw = 6.0f * logf((float)d + 1.0f + 1e-7f);
  float acc = 0.f;
  #pragma unroll
  for (int k = 0; k < NCOS; k++) {
    float ph = 1.57079632679489662f * (float)k;
    if (raw >= ph - PIF && raw <= ph + PIF) {
      acc += W[sh * NCOS + k] * (0.5f * cosf(raw - ph) + 0.5f);
    }
  }
  Keff[idx] = acc;
}

// ---------------- GEMM: syn[b][s][t] = sum_e S[b,t,e] * Cw[s,e]
// Block = 64 t-rows (lane = row) x full K as 25 slices of 100 e. Wave w owns s 5w..5w+4.
// BOTH S-slice (25.6KB) and Cw-slice (8KB) staged via global_load_lds width=16,
// double-buffered (67.6KB LDS -> 2 blocks/CU). Compute reads are LDS-ONLY (lgkmcnt):
// sv strided b128 (conflict-free, measured 0), cw wave-uniform broadcast b128 (free).
// vmcnt is touched ONLY by staging and drained once per slice at the barrier -> the
// next slice's DMA streams under the current slice's compute (no VMEM entanglement).
__global__ __launch_bounds__(256, 2) void gemm_syn_kernel(
    const float* __restrict__ S_e, const float* __restrict__ S_i,
    const float* __restrict__ CwP,
    float* __restrict__ synE, float* __restrict__ synI)
{
  const int b  = blockIdx.y;
  const int t0 = blockIdx.x * ROWS;
  __shared__ __align__(16) float sS[2 * ROWS * SLW];   // 2 x 6400 floats = 51.2 KB
  __shared__ __align__(16) float sC[2 * 2048];         // 2 x 8 KB (500 f4 used + pad)

  const int tid = threadIdx.x;
  const int l   = tid & 63;
  const int w   = tid >> 6;
  const int s0  = w * 5;
  int maxr = T_ - 1 - t0; if (maxr > ROWS - 1) maxr = ROWS - 1;

  const long baseE = ((long)(b * T_ + t0)) * ENO;
  const long baseI = ((long)(b * T_ + t0)) * INO;

  float4 acc4[5];
  #pragma unroll
  for (int j = 0; j < 5; j++) acc4[j] = make_float4(0.f, 0.f, 0.f, 0.f);

  // ---- stage slice z into buffer buf (S: 25 chunks of 64 f4; Cw: 8 chunks, tail-clamped)
  auto stage = [&](int z, int buf) {
    const bool isE = (z < 20);
    const float* __restrict__ src = isE ? (S_e + baseE + z * SLW)
                                        : (S_i + baseI + (z - 20) * SLW);
    const int rs = isE ? ENO : INO;
    float* dS = sS + buf * (ROWS * SLW);
    #pragma unroll
    for (int p = 0; p < 7; p++) {
      int c = w + 4 * p;
      if (c < 25) {
        int u = 64 * c + l;
        int r = u / 25, k = u - 25 * r;
        if (r > maxr) r = maxr;
        __builtin_amdgcn_global_load_lds(
            (const __attribute__((address_space(1))) void*)(src + (long)r * rs + 4 * k),
            (__attribute__((address_space(3))) void*)(dS + 256 * c), 16, 0, 0);
      }
    }
    const float* __restrict__ csrc = CwP + (long)z * (SUB * SLW);
    float* dC = sC + buf * 2048;
    #pragma unroll
    for (int p = 0; p < 2; p++) {
      int c = w + 4 * p;              // 0..7
      int u = 64 * c + l;
      if (u > 499) u = 499;           // tail lanes dup-write LDS pad (never read)
      __builtin_amdgcn_global_load_lds(
          (const __attribute__((address_space(1))) void*)(csrc + 4 * u),
          (__attribute__((address_space(3))) void*)(dC + 256 * c), 16, 0, 0);
    }
  };

  stage(0, 0);
  __syncthreads();   // vmcnt(0) drain

  for (int z = 0; z < NSL; z++) {
    const int cur = z & 1;
    // issue next slice's DMA first; it streams under this slice's compute
    if (z + 1 < NSL) stage(z + 1, cur ^ 1);

    // compute slice z (LDS-only reads)
    {
      const float* sb = sS + cur * (ROWS * SLW) + SLW * l;
      const float* cb = sC + cur * 2048 + s0 * SLW;
      #pragma unroll
      for (int e4 = 0; e4 < 25; e4++) {
        float4 sv = *(const float4*)&sb[4 * e4];
        #pragma unroll
        for (int j = 0; j < 5; j++) {
          float4 cw = *(const float4*)&cb[j * SLW + 4 * e4];   // uniform -> broadcast
          acc4[j].x += sv.x * cw.x;
          acc4[j].y += sv.y * cw.y;
          acc4[j].z += sv.z * cw.z;
          acc4[j].w += sv.w * cw.w;
        }
      }
    }

    // output at end of E (z==19) and end of I (z==24)
    if (z == 19 || z == 24) {
      float* __restrict__ dst = (z == 19) ? synE : synI;
      if (t0 + l < T_) {
        #pragma unroll
        for (int j = 0; j < 5; j++) {
          float a = acc4[j].x + acc4[j].y + acc4[j].z + acc4[j].w;
          dst[((long)b * SUB + s0 + j) * T_ + t0 + l] = a;
        }
      }
      #pragma unroll
      for (int j = 0; j < 5; j++) acc4[j] = make_float4(0.f, 0.f, 0.f, 0.f);
    }
    __syncthreads();   // drains staging vmcnt; buffers swap safely
  }
}

// ---------------- conv: pre[h,t] = sum_d Ke[h,d]*syn_e[t-d] + Ki[h,d]*syn_i[t-d]; tanh; combine over h
__global__ __launch_bounds__(256, 2) void conv_kernel(
    const float* __restrict__ synE, const float* __restrict__ synI,
    const float* __restrict__ Keff, const float* __restrict__ e2,
    const float* __restrict__ b1, float* __restrict__ sub_bst)
{
  const int chunk = blockIdx.x;       // 0..19
  const int s = blockIdx.y;
  const int b = blockIdx.z;
  const int cs = chunk * 1000;

  __shared__ __align__(16) float se[1200];
  __shared__ __align__(16) float si[1200];
  __shared__ __align__(16) float te[HID * TNO];
  __shared__ __align__(16) float ti[HID * TNO];
  __shared__ float se2[HID], sb[HID];

  const int tid = threadIdx.x;
  const float* __restrict__ pe = &synE[((long)b * SUB + s) * T_];
  const float* __restrict__ pin = &synI[((long)b * SUB + s) * T_];

  for (int i4 = tid; i4 < 300; i4 += 256) {
    int gt = cs - 200 + i4 * 4;
    float4 ve = make_float4(0.f, 0.f, 0.f, 0.f);
    float4 vi = make_float4(0.f, 0.f, 0.f, 0.f);
    if (gt >= 0) { ve = *(const float4*)&pe[gt]; vi = *(const float4*)&pin[gt]; }
    *(float4*)&se[i4 * 4] = ve;
    *(float4*)&si[i4 * 4] = vi;
  }
  const float* __restrict__ ke = &Keff[(long)s * HID * TNO];
  const float* __restrict__ ki = &Keff[((long)SUB + s) * HID * TNO];
  for (int i4 = tid; i4 < 500; i4 += 256) {
    *(float4*)&te[i4 * 4] = *(const float4*)&ke[i4 * 4];
    *(float4*)&ti[i4 * 4] = *(const float4*)&ki[i4 * 4];
  }
  if (tid < HID) { se2[tid] = e2[s * HID + tid]; sb[tid] = b1[s * HID + tid]; }
  __syncthreads();

  if (tid >= 250) return;
  const int lofs = 200 + 4 * tid;
  float so[4] = {0.f, 0.f, 0.f, 0.f};

  #pragma unroll
  for (int half = 0; half < 2; half++) {
    const int h0 = half * 5;
    float acc[5][4] = {};
    float we[8], wi[8];
    *(float4*)&we[4] = *(float4*)&se[lofs];
    *(float4*)&wi[4] = *(float4*)&si[lofs];
    for (int dstep = 0; dstep < 50; dstep++) {
      const int d0 = dstep * 4;
      *(float4*)&we[0] = *(float4*)&se[lofs - d0 - 4];
      *(float4*)&wi[0] = *(float4*)&si[lofs - d0 - 4];
      float4 tpe[5], tpi[5];
      #pragma unroll
      for (int h = 0; h < 5; h++) {
        tpe[h] = *(float4*)&te[(h0 + h) * TNO + d0];
        tpi[h] = *(float4*)&ti[(h0 + h) * TNO + d0];
      }
      #pragma unroll
      for (int dd = 0; dd < 4; dd++) {
        #pragma unroll
        for (int h = 0; h < 5; h++) {
          float tapeh = ((float*)&tpe[h])[dd];
          float tapih = ((float*)&tpi[h])[dd];
          #pragma unroll
          for (int j = 0; j < 4; j++) {
            acc[h][j] += tapeh * we[4 + j - dd];
            acc[h][j] += tapih * wi[4 + j - dd];
          }
        }
      }
      #pragma unroll
      for (int m = 0; m < 4; m++) { we[4 + m] = we[m]; wi[4 + m] = wi[m]; }
    }
    #pragma unroll
    for (int h = 0; h < 5; h++) {
      float eh = se2[h0 + h], bh = sb[h0 + h];
      #pragma unroll
      for (int j = 0; j < 4; j++) so[j] += eh * tanhf(acc[h][j] + bh);
    }
  }
  int t0 = cs + 4 * tid;
  *(float4*)&sub_bst[((long)b * SUB + s) * T_ + t0] = *(float4*)&so[0];
}

// ---------------- final: transpose sub_bst[b][s][t] -> sub_out[b][t][s], final[b][t] = sum_s + V_o
__global__ __launch_bounds__(256) void final_kernel(
    const float* __restrict__ sub_bst, const float* __restrict__ Vo,
    float* __restrict__ out_final, float* __restrict__ out_sub)
{
  int t = blockIdx.x * 256 + threadIdx.x;
  int b = blockIdx.y;
  if (t >= T_) return;
  float vo = Vo[0];
  float sum = 0.f;
  #pragma unroll
  for (int s = 0; s < SUB; s++) {
    float v = sub_bst[((long)b * SUB + s) * T_ + t];
    sum += v;
    out_sub[(((long)b * T_) + t) * SUB + s] = v;
  }
  out_final[(long)b * T_ + t] = sum + vo;
}

extern "C" void kernel_launch(void* const* d_in, const int* in_sizes, int n_in,
                              void* d_out, int out_size, void* d_ws, size_t ws_size,
                              hipStream_t stream)
{
  const float* S_e    = (const float*)d_in[0];
  const float* S_i    = (const float*)d_in[1];
  const int*   testp  = (const int*)d_in[3];
  const float* g_e    = (const float*)d_in[4];
  const float* g_i    = (const float*)d_in[5];
  const float* Es     = (const float*)d_in[6];
  const float* Is     = (const float*)d_in[7];
  const float* We     = (const float*)d_in[8];
  const float* Wi     = (const float*)d_in[9];
  const float* W2     = (const float*)d_in[10];
  const float* b1     = (const float*)d_in[11];
  const float* Ce_raw = (const float*)d_in[12];
  const float* Ci_raw = (const float*)d_in[13];
  const float* Vo     = (const float*)d_in[14];

  float* ws   = (float*)d_ws;
  float* CwP  = ws;                      // 25*20*100 = 50000
  float* Keff = ws + 50000;              // 80000
  float* e2   = ws + 130000;             // 200
  float* synE = ws + 130200;             // 1,600,000
  float* synI = synE + 1600000;          // 1,600,000
  float* subb = synI + 1600000;          // 1,600,000

  float* out     = (float*)d_out;
  float* o_final = out;                  // 80,000
  float* o_sub   = out + 80000;          // 1,600,000
  float* o_Ce    = out + 1680000;        // 40,000
  float* o_Ci    = out + 1720000;        // 10,000

  prep1_kernel<<<11, 256, 0, stream>>>(Ce_raw, Ci_raw, g_e, g_i, Es, Is, W2, testp,
                                       o_Ce, o_Ci, CwP, e2);
  prep2_kernel<<<(2 * SUB * HID * TNO + 255) / 256, 256, 0, stream>>>(We, Wi, Keff);
  gemm_syn_kernel<<<dim3((T_ + ROWS - 1) / ROWS, B_), 256, 0, stream>>>(S_e, S_i, CwP, synE, synI);
  conv_kernel<<<dim3(20, SUB, B_), 256, 0, stream>>>(synE, synI, Keff, e2, b1, subb);
  final_kernel<<<dim3((T_ + 255) / 256, B_), 256, 0, stream>>>(subb, Vo, o_final, o_sub);
}

// Round 8
// 4505.150 us; speedup vs baseline: 1.3330x; 1.3330x over previous
//
#include <hip/hip_runtime.h>
#include <math.h>

#define B_   4
#define T_   20000
#define SUB  20
#define ENO  2000
#define INO  500
#define HID  10
#define NCOS 24
#define TNO  200
#define NSL  25      // 20 E slices + 5 I slices, each 100 e wide
#define SLW  100     // slice width (floats)
#define BR   128     // t-rows per block

#define AS1 __attribute__((address_space(1)))
#define AS3 __attribute__((address_space(3)))

// ---------------- prep 1: softmax over subunit axis; CwP[z][s][100] = C*exp(scale); e2 = exp(W2)
__global__ __launch_bounds__(256) void prep1_kernel(
    const float* __restrict__ Ce_raw, const float* __restrict__ Ci_raw,
    const float* __restrict__ ge, const float* __restrict__ gi,
    const float* __restrict__ Es, const float* __restrict__ Is,
    const float* __restrict__ W2, const int* __restrict__ testp,
    float* __restrict__ outCe, float* __restrict__ outCi,
    float* __restrict__ CwP, float* __restrict__ e2)
{
  int idx = blockIdx.x * 256 + threadIdx.x;
  int test = *testp;
  float scale = test ? 10000.f : 1000.f;
  if (idx < ENO + INO) {
    const float* raw; const float* g; float* outC; int n, col, zbase; float sc;
    if (idx < ENO) { raw = Ce_raw; g = ge; outC = outCe; n = ENO; col = idx;       zbase = 0;  sc = expf(Es[col]); }
    else           { raw = Ci_raw; g = gi; outC = outCi; n = INO; col = idx - ENO; zbase = 20; sc = expf(Is[col]); }
    float v[SUB]; float m = -1e30f;
    #pragma unroll
    for (int s = 0; s < SUB; s++) {
      float x = raw[s * n + col];
      if (!test) x += g[s * n + col];
      x *= scale;
      v[s] = x; m = fmaxf(m, x);
    }
    float sum = 0.f;
    #pragma unroll
    for (int s = 0; s < SUB; s++) { v[s] = expf(v[s] - m); sum += v[s]; }
    float inv = 1.f / sum;
    int z = zbase + col / SLW, ep = col % SLW;
    #pragma unroll
    for (int s = 0; s < SUB; s++) {
      float c = v[s] * inv;
      outC[s * n + col] = c;
      CwP[((long)z * SUB + s) * SLW + ep] = c * sc;
    }
  } else if (idx < ENO + INO + SUB * HID) {
    int j = idx - (ENO + INO);
    e2[j] = expf(W2[j]);
  }
}

// ---------------- prep 2: effective kernels Keff[src][s][h][d] = sum_k W[s*HID+h,k] * basis(k,d)
__global__ __launch_bounds__(256) void prep2_kernel(
    const float* __restrict__ We, const float* __restrict__ Wi, float* __restrict__ Keff)
{
  int idx = blockIdx.x * 256 + threadIdx.x;
  if (idx >= 2 * SUB * HID * TNO) return;
  int d   = idx % TNO;
  int sh  = (idx / TNO) % (SUB * HID);
  int src = idx / (TNO * SUB * HID);
  const float* W = src ? Wi : We;           // [SUB*HID][NCOS]
  const float PIF = 3.14159265358979323846f;
  float raw = 6.0f * logf((float)d + 1.0f + 1e-7f);
  float acc = 0.f;
  #pragma unroll
  for (int k = 0; k < NCOS; k++) {
    float ph = 1.57079632679489662f * (float)k;
    if (raw >= ph - PIF && raw <= ph + PIF) {
      acc += W[sh * NCOS + k] * (0.5f * cosf(raw - ph) + 0.5f);
    }
  }
  Keff[idx] = acc;
}

// ---------------- GEMM: syn[b][s][t] = sum_e S[b,t,e] * Cw[s,e]
// Block = 128 t-rows, thread = rows l and l+64, wave w owns s 5w..5w+4.
// Simple m97-shape loop per 100-e slice: {stage S+Cw via global_load_lds -> barrier ->
// LDS-only compute -> barrier}. Cross-block TLP (2 blocks/CU) hides the drain.
// S tile rows padded to 32 f4 with XOR swizzle e4' = e4 ^ (row&7): conflict-free
// strided ds_read_b128 (write side is handled by pre-swizzling the per-lane GLOBAL
// source; pad/dup fetches are L2 hits, not HBM). Cw reads are wave-uniform broadcasts.
// All staging offsets precomputed once (slice-invariant) in unrolled register arrays.
__global__ __launch_bounds__(256, 2) void gemm_syn_kernel(
    const float* __restrict__ S_e, const float* __restrict__ S_i,
    const float* __restrict__ CwP,
    float* __restrict__ synE, float* __restrict__ synI)
{
  const int b  = blockIdx.y;
  const int t0 = blockIdx.x * BR;
  __shared__ __align__(16) float sS[BR * 128];   // 64 KB: row stride 32 f4, e4 swizzled
  __shared__ __align__(16) float sC[2048];       // 8 KB: [s][100] + pad

  const int tid = threadIdx.x;
  const int l   = tid & 63;
  const int w   = tid >> 6;
  const int s0  = w * 5;
  int maxr = T_ - 1 - t0; if (maxr > BR - 1) maxr = BR - 1;

  // per-thread staging offsets, invariant across slices (compile-time indexed after unroll)
  int offE[16], offI[16];
  #pragma unroll
  for (int p = 0; p < 16; p++) {
    int c   = w + 4 * p;               // chunk 0..63 (64 f4 each, lane l -> slot 64c+l)
    int row = 2 * c + (l >> 5);        // slot >> 5
    int e4  = (l & 31) ^ (row & 7);    // unswizzled e4 for this linear slot
    if (e4 > 24) e4 = 24;              // pad slot: dup-fetch (L2 hit), never read
    int r = row > maxr ? maxr : row;
    offE[p] = r * ENO + 4 * e4;
    offI[p] = r * INO + 4 * e4;
  }
  int offC[2];
  #pragma unroll
  for (int p = 0; p < 2; p++) {
    int u = 64 * (w + 4 * p) + l;
    if (u > 499) u = 499;
    offC[p] = 4 * u;
  }

  const long baseE = ((long)(b * T_ + t0)) * ENO;
  const long baseI = ((long)(b * T_ + t0)) * INO;

  float4 accA[5], accB[5];
  #pragma unroll
  for (int j = 0; j < 5; j++) { accA[j] = make_float4(0.f,0.f,0.f,0.f); accB[j] = make_float4(0.f,0.f,0.f,0.f); }

  for (int z = 0; z < NSL; z++) {
    const bool isE = (z < 20);
    const float* __restrict__ src  = isE ? (S_e + baseE + z * SLW)
                                         : (S_i + baseI + (z - 20) * SLW);
    const float* __restrict__ csrc = CwP + (long)z * (SUB * SLW);

    // ---- stage S (64 chunks) and Cw (8 chunks), direct global->LDS
    #pragma unroll
    for (int p = 0; p < 16; p++) {
      int c = w + 4 * p;
      int off = isE ? offE[p] : offI[p];
      __builtin_amdgcn_global_load_lds(
          (const AS1 void*)(src + off), (AS3 void*)(sS + 256 * c), 16, 0, 0);
    }
    #pragma unroll
    for (int p = 0; p < 2; p++) {
      int c = w + 4 * p;
      __builtin_amdgcn_global_load_lds(
          (const AS1 void*)(csrc + offC[p]), (AS3 void*)(sC + 256 * c), 16, 0, 0);
    }
    __syncthreads();   // vmcnt(0) drain -> tiles ready

    // ---- compute slice z (LDS-only: swizzled sv reads + broadcast cw reads)
    {
      const int xb = l & 7;
      const float* rA = sS + l * 128;
      const float* rB = sS + (l + 64) * 128;
      #pragma unroll
      for (int e4 = 0; e4 < 25; e4++) {
        int x = 4 * (e4 ^ xb);
        float4 svA = *(const float4*)&rA[x];
        float4 svB = *(const float4*)&rB[x];
        #pragma unroll
        for (int j = 0; j < 5; j++) {
          float4 cw = *(const float4*)&sC[(s0 + j) * SLW + 4 * e4];   // broadcast
          accA[j].x += svA.x * cw.x; accA[j].y += svA.y * cw.y;
          accA[j].z += svA.z * cw.z; accA[j].w += svA.w * cw.w;
          accB[j].x += svB.x * cw.x; accB[j].y += svB.y * cw.y;
          accB[j].z += svB.z * cw.z; accB[j].w += svB.w * cw.w;
        }
      }
    }

    // ---- output at end of E (z==19) and end of I (z==24)
    if (z == 19 || z == 24) {
      float* __restrict__ dst = (z == 19) ? synE : synI;
      #pragma unroll
      for (int j = 0; j < 5; j++) {
        float a = accA[j].x + accA[j].y + accA[j].z + accA[j].w;
        float c = accB[j].x + accB[j].y + accB[j].z + accB[j].w;
        long rowb = ((long)b * SUB + s0 + j) * T_;
        if (t0 + l      < T_) dst[rowb + t0 + l]      = a;
        if (t0 + 64 + l < T_) dst[rowb + t0 + 64 + l] = c;
      }
      #pragma unroll
      for (int j = 0; j < 5; j++) { accA[j] = make_float4(0.f,0.f,0.f,0.f); accB[j] = make_float4(0.f,0.f,0.f,0.f); }
    }
    __syncthreads();   // all reads done before next slice's staging overwrites
  }
}

// ---------------- conv: pre[h,t] = sum_d Ke[h,d]*syn_e[t-d] + Ki[h,d]*syn_i[t-d]; tanh; combine over h
__global__ __launch_bounds__(256, 2) void conv_kernel(
    const float* __restrict__ synE, const float* __restrict__ synI,
    const float* __restrict__ Keff, const float* __restrict__ e2,
    const float* __restrict__ b1, float* __restrict__ sub_bst)
{
  const int chunk = blockIdx.x;       // 0..19
  const int s = blockIdx.y;
  const int b = blockIdx.z;
  const int cs = chunk * 1000;

  __shared__ __align__(16) float se[1200];
  __shared__ __align__(16) float si[1200];
  __shared__ __align__(16) float te[HID * TNO];
  __shared__ __align__(16) float ti[HID * TNO];
  __shared__ float se2[HID], sb[HID];

  const int tid = threadIdx.x;
  const float* __restrict__ pe = &synE[((long)b * SUB + s) * T_];
  const float* __restrict__ pin = &synI[((long)b * SUB + s) * T_];

  for (int i4 = tid; i4 < 300; i4 += 256) {
    int gt = cs - 200 + i4 * 4;
    float4 ve = make_float4(0.f, 0.f, 0.f, 0.f);
    float4 vi = make_float4(0.f, 0.f, 0.f, 0.f);
    if (gt >= 0) { ve = *(const float4*)&pe[gt]; vi = *(const float4*)&pin[gt]; }
    *(float4*)&se[i4 * 4] = ve;
    *(float4*)&si[i4 * 4] = vi;
  }
  const float* __restrict__ ke = &Keff[(long)s * HID * TNO];
  const float* __restrict__ ki = &Keff[((long)SUB + s) * HID * TNO];
  for (int i4 = tid; i4 < 500; i4 += 256) {
    *(float4*)&te[i4 * 4] = *(const float4*)&ke[i4 * 4];
    *(float4*)&ti[i4 * 4] = *(const float4*)&ki[i4 * 4];
  }
  if (tid < HID) { se2[tid] = e2[s * HID + tid]; sb[tid] = b1[s * HID + tid]; }
  __syncthreads();

  if (tid >= 250) return;
  const int lofs = 200 + 4 * tid;
  float so[4] = {0.f, 0.f, 0.f, 0.f};

  #pragma unroll
  for (int half = 0; half < 2; half++) {
    const int h0 = half * 5;
    float acc[5][4] = {};
    float we[8], wi[8];
    *(float4*)&we[4] = *(float4*)&se[lofs];
    *(float4*)&wi[4] = *(float4*)&si[lofs];
    for (int dstep = 0; dstep < 50; dstep++) {
      const int d0 = dstep * 4;
      *(float4*)&we[0] = *(float4*)&se[lofs - d0 - 4];
      *(float4*)&wi[0] = *(float4*)&si[lofs - d0 - 4];
      float4 tpe[5], tpi[5];
      #pragma unroll
      for (int h = 0; h < 5; h++) {
        tpe[h] = *(float4*)&te[(h0 + h) * TNO + d0];
        tpi[h] = *(float4*)&ti[(h0 + h) * TNO + d0];
      }
      #pragma unroll
      for (int dd = 0; dd < 4; dd++) {
        #pragma unroll
        for (int h = 0; h < 5; h++) {
          float tapeh = ((float*)&tpe[h])[dd];
          float tapih = ((float*)&tpi[h])[dd];
          #pragma unroll
          for (int j = 0; j < 4; j++) {
            acc[h][j] += tapeh * we[4 + j - dd];
            acc[h][j] += tapih * wi[4 + j - dd];
          }
        }
      }
      #pragma unroll
      for (int m = 0; m < 4; m++) { we[4 + m] = we[m]; wi[4 + m] = wi[m]; }
    }
    #pragma unroll
    for (int h = 0; h < 5; h++) {
      float eh = se2[h0 + h], bh = sb[h0 + h];
      #pragma unroll
      for (int j = 0; j < 4; j++) so[j] += eh * tanhf(acc[h][j] + bh);
    }
  }
  int t0 = cs + 4 * tid;
  *(float4*)&sub_bst[((long)b * SUB + s) * T_ + t0] = *(float4*)&so[0];
}

// ---------------- final: transpose sub_bst[b][s][t] -> sub_out[b][t][s], final[b][t] = sum_s + V_o
__global__ __launch_bounds__(256) void final_kernel(
    const float* __restrict__ sub_bst, const float* __restrict__ Vo,
    float* __restrict__ out_final, float* __restrict__ out_sub)
{
  int t = blockIdx.x * 256 + threadIdx.x;
  int b = blockIdx.y;
  if (t >= T_) return;
  float vo = Vo[0];
  float sum = 0.f;
  #pragma unroll
  for (int s = 0; s < SUB; s++) {
    float v = sub_bst[((long)b * SUB + s) * T_ + t];
    sum += v;
    out_sub[(((long)b * T_) + t) * SUB + s] = v;
  }
  out_final[(long)b * T_ + t] = sum + vo;
}

extern "C" void kernel_launch(void* const* d_in, const int* in_sizes, int n_in,
                              void* d_out, int out_size, void* d_ws, size_t ws_size,
                              hipStream_t stream)
{
  const float* S_e    = (const float*)d_in[0];
  const float* S_i    = (const float*)d_in[1];
  const int*   testp  = (const int*)d_in[3];
  const float* g_e    = (const float*)d_in[4];
  const float* g_i    = (const float*)d_in[5];
  const float* Es     = (const float*)d_in[6];
  const float* Is     = (const float*)d_in[7];
  const float* We     = (const float*)d_in[8];
  const float* Wi     = (const float*)d_in[9];
  const float* W2     = (const float*)d_in[10];
  const float* b1     = (const float*)d_in[11];
  const float* Ce_raw = (const float*)d_in[12];
  const float* Ci_raw = (const float*)d_in[13];
  const float* Vo     = (const float*)d_in[14];

  float* ws   = (float*)d_ws;
  float* CwP  = ws;                      // 25*20*100 = 50000
  float* Keff = ws + 50000;              // 80000
  float* e2   = ws + 130000;             // 200
  float* synE = ws + 130200;             // 1,600,000
  float* synI = synE + 1600000;          // 1,600,000
  float* subb = synI + 1600000;          // 1,600,000

  float* out     = (float*)d_out;
  float* o_final = out;                  // 80,000
  float* o_sub   = out + 80000;          // 1,600,000
  float* o_Ce    = out + 1680000;        // 40,000
  float* o_Ci    = out + 1720000;        // 10,000

  prep1_kernel<<<11, 256, 0, stream>>>(Ce_raw, Ci_raw, g_e, g_i, Es, Is, W2, testp,
                                       o_Ce, o_Ci, CwP, e2);
  prep2_kernel<<<(2 * SUB * HID * TNO + 255) / 256, 256, 0, stream>>>(We, Wi, Keff);
  gemm_syn_kernel<<<dim3((T_ + BR - 1) / BR, B_), 256, 0, stream>>>(S_e, S_i, CwP, synE, synI);
  conv_kernel<<<dim3(20, SUB, B_), 256, 0, stream>>>(synE, synI, Keff, e2, b1, subb);
  final_kernel<<<dim3((T_ + 255) / 256, B_), 256, 0, stream>>>(subb, Vo, o_final, o_sub);
}

// Round 9
// 4437.261 us; speedup vs baseline: 1.3534x; 1.0153x over previous
//
#include <hip/hip_runtime.h>
#include <math.h>

#define B_   4
#define T_   20000
#define SUB  20
#define ENO  2000
#define INO  500
#define HID  10
#define NCOS 24
#define TNO  200
#define NSL  25      // 20 E slices + 5 I slices, each 100 e wide
#define SLW  100     // slice width (floats)
#define BR   128     // t-rows per block
#define CWS  2048    // padded Cw slice stride (floats)

#define AS1 __attribute__((address_space(1)))
#define AS3 __attribute__((address_space(3)))

// ---------------- prep 1: softmax over subunit axis; CwP[z*2048 + s*100 + ep] = C*exp(scale); e2 = exp(W2)
__global__ __launch_bounds__(256) void prep1_kernel(
    const float* __restrict__ Ce_raw, const float* __restrict__ Ci_raw,
    const float* __restrict__ ge, const float* __restrict__ gi,
    const float* __restrict__ Es, const float* __restrict__ Is,
    const float* __restrict__ W2, const int* __restrict__ testp,
    float* __restrict__ outCe, float* __restrict__ outCi,
    float* __restrict__ CwP, float* __restrict__ e2)
{
  int idx = blockIdx.x * 256 + threadIdx.x;
  int test = *testp;
  float scale = test ? 10000.f : 1000.f;
  if (idx < ENO + INO) {
    const float* raw; const float* g; float* outC; int n, col, zbase; float sc;
    if (idx < ENO) { raw = Ce_raw; g = ge; outC = outCe; n = ENO; col = idx;       zbase = 0;  sc = expf(Es[col]); }
    else           { raw = Ci_raw; g = gi; outC = outCi; n = INO; col = idx - ENO; zbase = 20; sc = expf(Is[col]); }
    float v[SUB]; float m = -1e30f;
    #pragma unroll
    for (int s = 0; s < SUB; s++) {
      float x = raw[s * n + col];
      if (!test) x += g[s * n + col];
      x *= scale;
      v[s] = x; m = fmaxf(m, x);
    }
    float sum = 0.f;
    #pragma unroll
    for (int s = 0; s < SUB; s++) { v[s] = expf(v[s] - m); sum += v[s]; }
    float inv = 1.f / sum;
    int z = zbase + col / SLW, ep = col % SLW;
    #pragma unroll
    for (int s = 0; s < SUB; s++) {
      float c = v[s] * inv;
      outC[s * n + col] = c;
      CwP[(long)z * CWS + s * SLW + ep] = c * sc;
    }
  } else if (idx < ENO + INO + SUB * HID) {
    int j = idx - (ENO + INO);
    e2[j] = expf(W2[j]);
  }
}

// ---------------- prep 2: effective kernels Keff[src][s][h][d] = sum_k W[s*HID+h,k] * basis(k,d)
__global__ __launch_bounds__(256) void prep2_kernel(
    const float* __restrict__ We, const float* __restrict__ Wi, float* __restrict__ Keff)
{
  int idx = blockIdx.x * 256 + threadIdx.x;
  if (idx >= 2 * SUB * HID * TNO) return;
  int d   = idx % TNO;
  int sh  = (idx / TNO) % (SUB * HID);
  int src = idx / (TNO * SUB * HID);
  const float* W = src ? Wi : We;           // [SUB*HID][NCOS]
  const float PIF = 3.14159265358979323846f;
  float raw = 6.0f * logf((float)d + 1.0f + 1e-7f);
  float acc = 0.f;
  #pragma unroll
  for (int k = 0; k < NCOS; k++) {
    float ph = 1.57079632679489662f * (float)k;
    if (raw >= ph - PIF && raw <= ph + PIF) {
      acc += W[sh * NCOS + k] * (0.5f * cosf(raw - ph) + 0.5f);
    }
  }
  Keff[idx] = acc;
}

// ---------------- GEMM: syn[b][s][t] = sum_e S[b,t,e] * Cw[s,e]
// R6 structure + ONE fix: Cw slice goes to LDS, so the compute phase is LDS-only and
// vmcnt is touched only by staging. Per-slice program order (pinned by sched_barrier):
//   (1) 2x cw float4 VMEM loads (OLDEST)          -> regs
//   (2) 13x global_load_lds S-tile DMA (younger)  -> sS
//   (3) ds_write cw  (compiler waits vmcnt(13): retires ONLY the older cw loads;
//       staging DMA stays in flight)
//   (4) __syncthreads (drains staging) -> (5) LDS-only compute -> (6) barrier.
// Block = 128 t-rows (thread: rows l and l+64), wave w owns s 5w..5w+4.
// sv: stride-100 b128 reads, quarter-wave 2-way aliasing = free (R6 measured 0).
// cw: wave-uniform broadcast b128 = free. 59KB LDS -> 2 blocks/CU; TLP hides drains.
__global__ __launch_bounds__(256, 2) void gemm_syn_kernel(
    const float* __restrict__ S_e, const float* __restrict__ S_i,
    const float* __restrict__ CwP,
    float* __restrict__ synE, float* __restrict__ synI)
{
  const int b  = blockIdx.y;
  const int t0 = blockIdx.x * BR;
  __shared__ __align__(16) float sS[BR * SLW];   // 51.2 KB linear, row stride 100
  __shared__ __align__(16) float sC[CWS];        // 8 KB

  const int tid = threadIdx.x;
  const int l   = tid & 63;
  const int w   = tid >> 6;
  const int s0  = w * 5;
  int maxr = T_ - 1 - t0; if (maxr > BR - 1) maxr = BR - 1;

  const long baseE = ((long)(b * T_ + t0)) * ENO;
  const long baseI = ((long)(b * T_ + t0)) * INO;

  float4 accA[5], accB[5];
  #pragma unroll
  for (int j = 0; j < 5; j++) { accA[j] = make_float4(0.f,0.f,0.f,0.f); accB[j] = make_float4(0.f,0.f,0.f,0.f); }

  for (int z = 0; z < NSL; z++) {
    const bool isE = (z < 20);
    const float* __restrict__ src = isE ? (S_e + baseE + z * SLW)
                                        : (S_i + baseI + (z - 20) * SLW);
    const int rs = isE ? ENO : INO;
    const float* __restrict__ csrc = CwP + (long)z * CWS;

    // (1) cw slice -> registers (the OLDEST VMEM ops of this iteration)
    float4 cw0 = *(const float4*)&csrc[4 * tid];
    float4 cw1 = *(const float4*)&csrc[4 * (tid + 256)];
    __builtin_amdgcn_sched_barrier(0);

    // (2) S tile staging: 50 chunks of 64 float4, direct global->LDS (linear dest)
    #pragma unroll
    for (int p = 0; p < 13; p++) {
      int c = w + 4 * p;
      if (c < 50) {
        int u = 64 * c + l;
        int r = u / 25, k = u - 25 * r;
        if (r > maxr) r = maxr;
        __builtin_amdgcn_global_load_lds(
            (const AS1 void*)(src + (long)r * rs + 4 * k),
            (AS3 void*)(sS + 256 * c), 16, 0, 0);
      }
    }
    __builtin_amdgcn_sched_barrier(0);

    // (3) commit cw to LDS: waits only the two older cw loads (FIFO), staging stays in flight
    *(float4*)&sC[4 * tid] = cw0;
    *(float4*)&sC[4 * (tid + 256)] = cw1;

    __syncthreads();   // drains staging DMA; tiles ready

    // (5) compute slice z: LDS-only
    {
      const float* rA = sS + l * SLW;
      const float* rB = sS + (l + 64) * SLW;
      const float* cb = sC + s0 * SLW;
      #pragma unroll
      for (int e4 = 0; e4 < 25; e4++) {
        float4 svA = *(const float4*)&rA[4 * e4];
        float4 svB = *(const float4*)&rB[4 * e4];
        #pragma unroll
        for (int j = 0; j < 5; j++) {
          float4 cw = *(const float4*)&cb[j * SLW + 4 * e4];   // wave-uniform broadcast
          accA[j].x += svA.x * cw.x; accA[j].y += svA.y * cw.y;
          accA[j].z += svA.z * cw.z; accA[j].w += svA.w * cw.w;
          accB[j].x += svB.x * cw.x; accB[j].y += svB.y * cw.y;
          accB[j].z += svB.z * cw.z; accB[j].w += svB.w * cw.w;
        }
      }
    }

    // output at end of E (z==19) and end of I (z==24)
    if (z == 19 || z == 24) {
      float* __restrict__ dst = (z == 19) ? synE : synI;
      #pragma unroll
      for (int j = 0; j < 5; j++) {
        float a = accA[j].x + accA[j].y + accA[j].z + accA[j].w;
        float c = accB[j].x + accB[j].y + accB[j].z + accB[j].w;
        long rowb = ((long)b * SUB + s0 + j) * T_;
        if (t0 + l      < T_) dst[rowb + t0 + l]      = a;
        if (t0 + 64 + l < T_) dst[rowb + t0 + 64 + l] = c;
      }
      #pragma unroll
      for (int j = 0; j < 5; j++) { accA[j] = make_float4(0.f,0.f,0.f,0.f); accB[j] = make_float4(0.f,0.f,0.f,0.f); }
    }
    __syncthreads();   // all LDS reads done before next slice's staging overwrites
  }
}

// ---------------- conv: pre[h,t] = sum_d Ke[h,d]*syn_e[t-d] + Ki[h,d]*syn_i[t-d]; tanh; combine over h
__global__ __launch_bounds__(256, 2) void conv_kernel(
    const float* __restrict__ synE, const float* __restrict__ synI,
    const float* __restrict__ Keff, const float* __restrict__ e2,
    const float* __restrict__ b1, float* __restrict__ sub_bst)
{
  const int chunk = blockIdx.x;       // 0..19
  const int s = blockIdx.y;
  const int b = blockIdx.z;
  const int cs = chunk * 1000;

  __shared__ __align__(16) float se[1200];
  __shared__ __align__(16) float si[1200];
  __shared__ __align__(16) float te[HID * TNO];
  __shared__ __align__(16) float ti[HID * TNO];
  __shared__ float se2[HID], sb[HID];

  const int tid = threadIdx.x;
  const float* __restrict__ pe = &synE[((long)b * SUB + s) * T_];
  const float* __restrict__ pin = &synI[((long)b * SUB + s) * T_];

  for (int i4 = tid; i4 < 300; i4 += 256) {
    int gt = cs - 200 + i4 * 4;
    float4 ve = make_float4(0.f, 0.f, 0.f, 0.f);
    float4 vi = make_float4(0.f, 0.f, 0.f, 0.f);
    if (gt >= 0) { ve = *(const float4*)&pe[gt]; vi = *(const float4*)&pin[gt]; }
    *(float4*)&se[i4 * 4] = ve;
    *(float4*)&si[i4 * 4] = vi;
  }
  const float* __restrict__ ke = &Keff[(long)s * HID * TNO];
  const float* __restrict__ ki = &Keff[((long)SUB + s) * HID * TNO];
  for (int i4 = tid; i4 < 500; i4 += 256) {
    *(float4*)&te[i4 * 4] = *(const float4*)&ke[i4 * 4];
    *(float4*)&ti[i4 * 4] = *(const float4*)&ki[i4 * 4];
  }
  if (tid < HID) { se2[tid] = e2[s * HID + tid]; sb[tid] = b1[s * HID + tid]; }
  __syncthreads();

  if (tid >= 250) return;
  const int lofs = 200 + 4 * tid;
  float so[4] = {0.f, 0.f, 0.f, 0.f};

  #pragma unroll
  for (int half = 0; half < 2; half++) {
    const int h0 = half * 5;
    float acc[5][4] = {};
    float we[8], wi[8];
    *(float4*)&we[4] = *(float4*)&se[lofs];
    *(float4*)&wi[4] = *(float4*)&si[lofs];
    for (int dstep = 0; dstep < 50; dstep++) {
      const int d0 = dstep * 4;
      *(float4*)&we[0] = *(float4*)&se[lofs - d0 - 4];
      *(float4*)&wi[0] = *(float4*)&si[lofs - d0 - 4];
      float4 tpe[5], tpi[5];
      #pragma unroll
      for (int h = 0; h < 5; h++) {
        tpe[h] = *(float4*)&te[(h0 + h) * TNO + d0];
        tpi[h] = *(float4*)&ti[(h0 + h) * TNO + d0];
      }
      #pragma unroll
      for (int dd = 0; dd < 4; dd++) {
        #pragma unroll
        for (int h = 0; h < 5; h++) {
          float tapeh = ((float*)&tpe[h])[dd];
          float tapih = ((float*)&tpi[h])[dd];
          #pragma unroll
          for (int j = 0; j < 4; j++) {
            acc[h][j] += tapeh * we[4 + j - dd];
            acc[h][j] += tapih * wi[4 + j - dd];
          }
        }
      }
      #pragma unroll
      for (int m = 0; m < 4; m++) { we[4 + m] = we[m]; wi[4 + m] = wi[m]; }
    }
    #pragma unroll
    for (int h = 0; h < 5; h++) {
      float eh = se2[h0 + h], bh = sb[h0 + h];
      #pragma unroll
      for (int j = 0; j < 4; j++) so[j] += eh * tanhf(acc[h][j] + bh);
    }
  }
  int t0 = cs + 4 * tid;
  *(float4*)&sub_bst[((long)b * SUB + s) * T_ + t0] = *(float4*)&so[0];
}

// ---------------- final: transpose sub_bst[b][s][t] -> sub_out[b][t][s], final[b][t] = sum_s + V_o
__global__ __launch_bounds__(256) void final_kernel(
    const float* __restrict__ sub_bst, const float* __restrict__ Vo,
    float* __restrict__ out_final, float* __restrict__ out_sub)
{
  int t = blockIdx.x * 256 + threadIdx.x;
  int b = blockIdx.y;
  if (t >= T_) return;
  float vo = Vo[0];
  float sum = 0.f;
  #pragma unroll
  for (int s = 0; s < SUB; s++) {
    float v = sub_bst[((long)b * SUB + s) * T_ + t];
    sum += v;
    out_sub[(((long)b * T_) + t) * SUB + s] = v;
  }
  out_final[(long)b * T_ + t] = sum + vo;
}

extern "C" void kernel_launch(void* const* d_in, const int* in_sizes, int n_in,
                              void* d_out, int out_size, void* d_ws, size_t ws_size,
                              hipStream_t stream)
{
  const float* S_e    = (const float*)d_in[0];
  const float* S_i    = (const float*)d_in[1];
  const int*   testp  = (const int*)d_in[3];
  const float* g_e    = (const float*)d_in[4];
  const float* g_i    = (const float*)d_in[5];
  const float* Es     = (const float*)d_in[6];
  const float* Is     = (const float*)d_in[7];
  const float* We     = (const float*)d_in[8];
  const float* Wi     = (const float*)d_in[9];
  const float* W2     = (const float*)d_in[10];
  const float* b1     = (const float*)d_in[11];
  const float* Ce_raw = (const float*)d_in[12];
  const float* Ci_raw = (const float*)d_in[13];
  const float* Vo     = (const float*)d_in[14];

  float* ws   = (float*)d_ws;
  float* CwP  = ws;                      // 25*2048 = 51200
  float* Keff = ws + 51200;              // 80000
  float* e2   = ws + 131200;             // 200
  float* synE = ws + 131400;             // 1,600,000
  float* synI = synE + 1600000;          // 1,600,000
  float* subb = synI + 1600000;          // 1,600,000

  float* out     = (float*)d_out;
  float* o_final = out;                  // 80,000
  float* o_sub   = out + 80000;          // 1,600,000
  float* o_Ce    = out + 1680000;        // 40,000
  float* o_Ci    = out + 1720000;        // 10,000

  prep1_kernel<<<11, 256, 0, stream>>>(Ce_raw, Ci_raw, g_e, g_i, Es, Is, W2, testp,
                                       o_Ce, o_Ci, CwP, e2);
  prep2_kernel<<<(2 * SUB * HID * TNO + 255) / 256, 256, 0, stream>>>(We, Wi, Keff);
  gemm_syn_kernel<<<dim3((T_ + BR - 1) / BR, B_), 256, 0, stream>>>(S_e, S_i, CwP, synE, synI);
  conv_kernel<<<dim3(20, SUB, B_), 256, 0, stream>>>(synE, synI, Keff, e2, b1, subb);
  final_kernel<<<dim3((T_ + 255) / 256, B_), 256, 0, stream>>>(subb, Vo, o_final, o_sub);
}